// Round 1
// baseline (399.541 us; speedup 1.0000x reference)
//
#include <hip/hip_runtime.h>
#include <float.h>
#include <math.h>

// Problem constants
#define TT 4096          // tokens = B*S
#define HH 1024          // hidden
#define II 512           // expert ffn hidden
#define E_R 32
#define E_T 40
#define TOPK 6
#define SCALE_F 2.5f

typedef __bf16 bf16x8 __attribute__((ext_vector_type(8)));
typedef float f32x4 __attribute__((ext_vector_type(4)));

__device__ inline unsigned short f2bf(float f) {
  unsigned int u = __builtin_bit_cast(unsigned int, f);
  unsigned int r = (u + 0x7FFFu + ((u >> 16) & 1u)) >> 16;
  return (unsigned short)r;
}

__device__ inline uint4 cvt8(float4 a, float4 b) {
  uint4 v;
  v.x = (unsigned)f2bf(a.x) | ((unsigned)f2bf(a.y) << 16);
  v.y = (unsigned)f2bf(a.z) | ((unsigned)f2bf(a.w) << 16);
  v.z = (unsigned)f2bf(b.x) | ((unsigned)f2bf(b.y) << 16);
  v.w = (unsigned)f2bf(b.z) | ((unsigned)f2bf(b.w) << 16);
  return v;
}

// LDS tile helpers: [64 rows][64 bf16], row stride 128 B, XOR swizzle on byte bits 4..6
__device__ inline void lds_store16(unsigned short* base, int row, int c8, uint4 v) {
  int byte = (row * 128 + c8 * 16) ^ ((row & 7) << 4);
  *reinterpret_cast<uint4*>(reinterpret_cast<char*>(base) + byte) = v;
}
__device__ inline bf16x8 lds_frag(const unsigned short* base, int row, int kb) {
  int byte = (row * 128 + kb * 2) ^ ((row & 7) << 4);
  uint4 v = *reinterpret_cast<const uint4*>(reinterpret_cast<const char*>(base) + byte);
  return __builtin_bit_cast(bf16x8, v);
}

__device__ inline f32x4 mfma16(bf16x8 a, bf16x8 b, f32x4 c) {
  return __builtin_amdgcn_mfma_f32_16x16x32_bf16(a, b, c, 0, 0, 0);
}

// ---------------- kernel 1: convert x fp32 -> bf16 ----------------
__global__ void k_convert_x(const float* __restrict__ x, unsigned short* __restrict__ xb) {
  int i = blockIdx.x * 256 + threadIdx.x;          // one per 8 elements
  const float4* p = reinterpret_cast<const float4*>(x) + (size_t)i * 2;
  float4 a = p[0], b = p[1];
  reinterpret_cast<uint4*>(xb)[i] = cvt8(a, b);
}

// ---------------- kernel 2: router ----------------
__global__ void k_router(const float* __restrict__ x, const float* __restrict__ wcls,
                         const float* __restrict__ bias,
                         float* __restrict__ zero_w, int* __restrict__ counts,
                         int* __restrict__ tok_list, float* __restrict__ wt_list) {
  int t = blockIdx.x;
  int tid = threadIdx.x;
  __shared__ float xs[HH];
  __shared__ float logits[E_T];
  __shared__ float scoreS[E_T];
  __shared__ float selS[E_T];
  reinterpret_cast<float4*>(xs)[tid] = reinterpret_cast<const float4*>(x + (size_t)t * HH)[tid];
  __syncthreads();
  int wave = tid >> 6, lane = tid & 63;
  for (int ei = 0; ei < 10; ++ei) {
    int e = wave * 10 + ei;
    float s = 0.f;
    for (int h = lane; h < HH; h += 64) s += xs[h] * wcls[e * HH + h];
    for (int o = 32; o; o >>= 1) s += __shfl_xor(s, o);
    if (lane == 0) logits[e] = s;
  }
  __syncthreads();
  if (tid == 0) {
    float m = logits[0];
    for (int e = 1; e < E_T; ++e) m = fmaxf(m, logits[e]);
    float den = 0.f;
    for (int e = 0; e < E_T; ++e) den += expf(logits[e] - m);
    float inv = 1.f / den;
    for (int e = 0; e < E_T; ++e) {
      float sc = expf(logits[e] - m) * inv;
      scoreS[e] = sc;
      selS[e] = sc + bias[e];
    }
    float zw = 0.f;
    for (int k = 0; k < TOPK; ++k) {
      int bj = 0; float bv = -FLT_MAX;
      for (int e = 0; e < E_T; ++e) {
        float v = selS[e];
        if (v > bv) { bv = v; bj = e; }
      }
      selS[bj] = -FLT_MAX;
      float wgt = scoreS[bj] * SCALE_F;
      if (bj >= E_R) {
        zw += wgt;
      } else {
        int p = atomicAdd(&counts[bj], 1);
        tok_list[bj * TT + p] = t;
        wt_list[bj * TT + p] = wgt;
      }
    }
    zero_w[t] = zw;
  }
}

// ---------------- kernel 3: prefix scan of counts ----------------
__global__ void k_scan(const int* __restrict__ counts, int* __restrict__ offsets) {
  if (threadIdx.x == 0) {
    int s = 0;
    for (int e = 0; e < E_R; ++e) { offsets[e] = s; s += counts[e]; }
    offsets[E_R] = s;
  }
}

// ---------------- kernel 4: out = x * zero_w ----------------
__global__ void k_init_out(const float* __restrict__ x, const float* __restrict__ zero_w,
                           float* __restrict__ out) {
  int i = blockIdx.x * 256 + threadIdx.x;          // one per 4 floats
  int t = i >> 8;                                  // 256 float4 per row
  float zw = zero_w[t];
  float4 v = reinterpret_cast<const float4*>(x)[i];
  v.x *= zw; v.y *= zw; v.z *= zw; v.w *= zw;
  reinterpret_cast<float4*>(out)[i] = v;
}

// ---------------- kernel 5: grouped GEMM1 + SiLU*up -> inter (bf16) ----------------
// block: 64 token-rows x (64 gate cols + 64 up cols), K = 1024
__global__ __launch_bounds__(256) void k_gemm1(
    const unsigned short* __restrict__ xb, const float* __restrict__ gup,
    const int* __restrict__ tok_list, const int* __restrict__ counts,
    const int* __restrict__ offsets, unsigned short* __restrict__ inter) {
  const int e = blockIdx.z;
  const int cnt = counts[e];
  const int row0 = blockIdx.y * 64;
  if (row0 >= cnt) return;
  const int n0 = blockIdx.x * 64;
  const int off = offsets[e];
  const int tid = threadIdx.x;
  const int lane = tid & 63;
  const int wave = tid >> 6;
  const int wr = wave >> 1, wc = wave & 1;

  __shared__ __align__(16) unsigned short lA[64 * 64];
  __shared__ __align__(16) unsigned short lBg[64 * 64];
  __shared__ __align__(16) unsigned short lBu[64 * 64];
  __shared__ int toks[64];

  if (tid < 64) {
    int r = row0 + tid;
    toks[tid] = tok_list[e * TT + (r < cnt ? r : cnt - 1)];
  }
  __syncthreads();

  f32x4 accg[2][2] = {}; f32x4 accu[2][2] = {};

  for (int k0 = 0; k0 < HH; k0 += 64) {
    #pragma unroll
    for (int c = tid; c < 512; c += 256) {
      int row = c >> 3, c8 = c & 7;
      uint4 v = *reinterpret_cast<const uint4*>(xb + (size_t)toks[row] * HH + (k0 + c8 * 8));
      lds_store16(lA, row, c8, v);
      const float4* p = reinterpret_cast<const float4*>(
          gup + ((size_t)e * 1024 + (n0 + row)) * HH + (k0 + c8 * 8));
      lds_store16(lBg, row, c8, cvt8(p[0], p[1]));
      const float4* q = reinterpret_cast<const float4*>(
          gup + ((size_t)e * 1024 + (512 + n0 + row)) * HH + (k0 + c8 * 8));
      lds_store16(lBu, row, c8, cvt8(q[0], q[1]));
    }
    __syncthreads();
    #pragma unroll
    for (int ks = 0; ks < 2; ++ks) {
      int kb = ks * 32 + ((lane >> 4) << 3);
      bf16x8 a0 = lds_frag(lA, wr * 32 + (lane & 15), kb);
      bf16x8 a1 = lds_frag(lA, wr * 32 + 16 + (lane & 15), kb);
      bf16x8 g0 = lds_frag(lBg, wc * 32 + (lane & 15), kb);
      bf16x8 g1 = lds_frag(lBg, wc * 32 + 16 + (lane & 15), kb);
      bf16x8 u0 = lds_frag(lBu, wc * 32 + (lane & 15), kb);
      bf16x8 u1 = lds_frag(lBu, wc * 32 + 16 + (lane & 15), kb);
      accg[0][0] = mfma16(a0, g0, accg[0][0]);
      accg[0][1] = mfma16(a0, g1, accg[0][1]);
      accg[1][0] = mfma16(a1, g0, accg[1][0]);
      accg[1][1] = mfma16(a1, g1, accg[1][1]);
      accu[0][0] = mfma16(a0, u0, accu[0][0]);
      accu[0][1] = mfma16(a0, u1, accu[0][1]);
      accu[1][0] = mfma16(a1, u0, accu[1][0]);
      accu[1][1] = mfma16(a1, u1, accu[1][1]);
    }
    __syncthreads();
  }

  #pragma unroll
  for (int i = 0; i < 2; ++i)
    #pragma unroll
    for (int j = 0; j < 2; ++j)
      #pragma unroll
      for (int r = 0; r < 4; ++r) {
        int rloc = wr * 32 + i * 16 + ((lane >> 4) << 2) + r;
        int grow = row0 + rloc;
        if (grow < cnt) {
          int col = n0 + wc * 32 + j * 16 + (lane & 15);
          float g = accg[i][j][r], u = accu[i][j][r];
          float act = g * (1.f / (1.f + __expf(-g))) * u;
          inter[(size_t)(off + grow) * II + col] = f2bf(act);
        }
      }
}

// ---------------- kernel 6: grouped GEMM2, scatter-add into out ----------------
// block: 64 rows x 64 out cols, K = 512
__global__ __launch_bounds__(256) void k_gemm2(
    const unsigned short* __restrict__ inter, const float* __restrict__ dwn,
    const int* __restrict__ tok_list, const float* __restrict__ wt_list,
    const int* __restrict__ counts, const int* __restrict__ offsets,
    float* __restrict__ out) {
  const int e = blockIdx.z;
  const int cnt = counts[e];
  const int row0 = blockIdx.y * 64;
  if (row0 >= cnt) return;
  const int n0 = blockIdx.x * 64;
  const int off = offsets[e];
  const int tid = threadIdx.x;
  const int lane = tid & 63;
  const int wave = tid >> 6;
  const int wr = wave >> 1, wc = wave & 1;

  __shared__ __align__(16) unsigned short lA[64 * 64];
  __shared__ __align__(16) unsigned short lB[64 * 64];
  __shared__ int toks[64];
  __shared__ float wts[64];

  if (tid < 64) {
    int r = row0 + tid;
    int rc = r < cnt ? r : cnt - 1;
    toks[tid] = tok_list[e * TT + rc];
    wts[tid] = (r < cnt) ? wt_list[e * TT + rc] : 0.f;
  }
  __syncthreads();

  f32x4 acc[2][2] = {};

  for (int k0 = 0; k0 < II; k0 += 64) {
    #pragma unroll
    for (int c = tid; c < 512; c += 256) {
      int row = c >> 3, c8 = c & 7;
      int rr = row0 + row; rr = rr < cnt ? rr : cnt - 1;
      uint4 v = *reinterpret_cast<const uint4*>(inter + (size_t)(off + rr) * II + (k0 + c8 * 8));
      lds_store16(lA, row, c8, v);
      const float4* p = reinterpret_cast<const float4*>(
          dwn + ((size_t)e * HH + (n0 + row)) * II + (k0 + c8 * 8));
      lds_store16(lB, row, c8, cvt8(p[0], p[1]));
    }
    __syncthreads();
    #pragma unroll
    for (int ks = 0; ks < 2; ++ks) {
      int kb = ks * 32 + ((lane >> 4) << 3);
      bf16x8 a0 = lds_frag(lA, wr * 32 + (lane & 15), kb);
      bf16x8 a1 = lds_frag(lA, wr * 32 + 16 + (lane & 15), kb);
      bf16x8 b0 = lds_frag(lB, wc * 32 + (lane & 15), kb);
      bf16x8 b1 = lds_frag(lB, wc * 32 + 16 + (lane & 15), kb);
      acc[0][0] = mfma16(a0, b0, acc[0][0]);
      acc[0][1] = mfma16(a0, b1, acc[0][1]);
      acc[1][0] = mfma16(a1, b0, acc[1][0]);
      acc[1][1] = mfma16(a1, b1, acc[1][1]);
    }
    __syncthreads();
  }

  #pragma unroll
  for (int i = 0; i < 2; ++i)
    #pragma unroll
    for (int j = 0; j < 2; ++j)
      #pragma unroll
      for (int r = 0; r < 4; ++r) {
        int rloc = wr * 32 + i * 16 + ((lane >> 4) << 2) + r;
        int grow = row0 + rloc;
        if (grow < cnt) {
          int h = n0 + wc * 32 + j * 16 + (lane & 15);
          unsafeAtomicAdd(&out[(size_t)toks[rloc] * HH + h], acc[i][j][r] * wts[rloc]);
        }
      }
}

// ---------------- ws layout ----------------
// xb      : TT*HH bf16          =  8,388,608 B   @ 0
// zero_w  : TT f32              =     16,384 B   @ 8,388,608
// counts  : 32 i32              =        128 B   @ 8,404,992
// offsets : 33 i32 (pad 256)    =        256 B   @ 8,405,120
// tok_list: 32*TT i32           =    524,288 B   @ 8,405,376
// wt_list : 32*TT f32           =    524,288 B   @ 8,929,664
// inter   : 24576*II bf16       = 25,165,824 B   @ 9,453,952
// total ~= 34.6 MB

extern "C" void kernel_launch(void* const* d_in, const int* in_sizes, int n_in,
                              void* d_out, int out_size, void* d_ws, size_t ws_size,
                              hipStream_t stream) {
  const float* x    = (const float*)d_in[0];
  const float* wcls = (const float*)d_in[1];
  const float* bias = (const float*)d_in[2];
  const float* gup  = (const float*)d_in[3];
  const float* dwn  = (const float*)d_in[4];
  float* out = (float*)d_out;

  char* w = (char*)d_ws;
  unsigned short* xb   = (unsigned short*)(w + 0);
  float* zero_w        = (float*)(w + 8388608);
  int* counts          = (int*)(w + 8404992);
  int* offsets         = (int*)(w + 8405120);
  int* tok_list        = (int*)(w + 8405376);
  float* wt_list       = (float*)(w + 8929664);
  unsigned short* inter = (unsigned short*)(w + 9453952);

  hipMemsetAsync(counts, 0, E_R * sizeof(int), stream);
  k_convert_x<<<2048, 256, 0, stream>>>(x, xb);
  k_router<<<TT, 256, 0, stream>>>(x, wcls, bias, zero_w, counts, tok_list, wt_list);
  k_scan<<<1, 64, 0, stream>>>(counts, offsets);
  k_init_out<<<4096, 256, 0, stream>>>(x, zero_w, out);
  k_gemm1<<<dim3(8, 64, E_R), 256, 0, stream>>>(xb, gup, tok_list, counts, offsets, inter);
  k_gemm2<<<dim3(16, 64, E_R), 256, 0, stream>>>(inter, dwn, tok_list, wt_list, counts, offsets, out);
}

// Round 2
// 271.929 us; speedup vs baseline: 1.4693x; 1.4693x over previous
//
#include <hip/hip_runtime.h>
#include <float.h>
#include <math.h>

// Problem constants
#define TT 4096          // tokens = B*S
#define HH 1024          // hidden
#define II 512           // expert ffn hidden
#define E_R 32
#define E_T 40
#define TOPK 6
#define SCALE_F 2.5f

typedef __bf16 bf16x8 __attribute__((ext_vector_type(8)));
typedef float f32x4 __attribute__((ext_vector_type(4)));

__device__ inline unsigned short f2bf(float f) {
  unsigned int u = __builtin_bit_cast(unsigned int, f);
  unsigned int r = (u + 0x7FFFu + ((u >> 16) & 1u)) >> 16;
  return (unsigned short)r;
}

__device__ inline uint4 cvt8(float4 a, float4 b) {
  uint4 v;
  v.x = (unsigned)f2bf(a.x) | ((unsigned)f2bf(a.y) << 16);
  v.y = (unsigned)f2bf(a.z) | ((unsigned)f2bf(a.w) << 16);
  v.z = (unsigned)f2bf(b.x) | ((unsigned)f2bf(b.y) << 16);
  v.w = (unsigned)f2bf(b.z) | ((unsigned)f2bf(b.w) << 16);
  return v;
}

// LDS tile helpers: [64 rows][64 bf16], row stride 128 B, XOR swizzle on byte bits 4..6
__device__ inline void lds_store16(unsigned short* base, int row, int c8, uint4 v) {
  int byte = (row * 128 + c8 * 16) ^ ((row & 7) << 4);
  *reinterpret_cast<uint4*>(reinterpret_cast<char*>(base) + byte) = v;
}
__device__ inline bf16x8 lds_frag(const unsigned short* base, int row, int kb) {
  int byte = (row * 128 + kb * 2) ^ ((row & 7) << 4);
  uint4 v = *reinterpret_cast<const uint4*>(reinterpret_cast<const char*>(base) + byte);
  return __builtin_bit_cast(bf16x8, v);
}

__device__ inline f32x4 mfma16(bf16x8 a, bf16x8 b, f32x4 c) {
  return __builtin_amdgcn_mfma_f32_16x16x32_bf16(a, b, c, 0, 0, 0);
}

// ---------------- kernel 1: convert x fp32 -> bf16 ----------------
__global__ void k_convert_x(const float* __restrict__ x, unsigned short* __restrict__ xb) {
  int i = blockIdx.x * 256 + threadIdx.x;          // one per 8 elements
  const float4* p = reinterpret_cast<const float4*>(x) + (size_t)i * 2;
  float4 a = p[0], b = p[1];
  reinterpret_cast<uint4*>(xb)[i] = cvt8(a, b);
}

// ---------------- kernel 2a: router logits (fp32 GEMV, wave per token) ----------------
// grid 1024 x 256 threads. Each wave owns one token; x chunk in regs; wcls chunk in LDS.
__global__ __launch_bounds__(256) void k_logits(const float* __restrict__ x,
                                                const float* __restrict__ wcls,
                                                float* __restrict__ logits) {
  __shared__ float4 ws4[E_T * 64];                 // 40 experts x 256-float K-chunk = 40 KB
  const int tid = threadIdx.x;
  const int lane = tid & 63;
  const int wave = tid >> 6;
  const int token = blockIdx.x * 4 + wave;
  const float4* x4 = reinterpret_cast<const float4*>(x);
  const float4* w4 = reinterpret_cast<const float4*>(wcls);

  float acc[E_T];
  #pragma unroll
  for (int e = 0; e < E_T; ++e) acc[e] = 0.f;

  for (int c = 0; c < 4; ++c) {                    // 4 K-chunks of 256 floats
    if (c) __syncthreads();
    #pragma unroll
    for (int j = 0; j < 10; ++j) {                 // stage wcls chunk: 2560 float4 / 256 thr
      int v = tid + j * 256;
      int e = v >> 6, kq = v & 63;
      ws4[v] = w4[e * 256 + c * 64 + kq];
    }
    float4 xv = x4[(size_t)token * 256 + c * 64 + lane];
    __syncthreads();
    #pragma unroll
    for (int e = 0; e < E_T; ++e) {
      float4 w = ws4[e * 64 + lane];               // b128, stride-1 across lanes
      acc[e] += xv.x * w.x + xv.y * w.y + xv.z * w.z + xv.w * w.w;
    }
  }

  float mine = 0.f;
  #pragma unroll
  for (int e = 0; e < E_T; ++e) {
    float r = acc[e];
    #pragma unroll
    for (int o = 32; o; o >>= 1) r += __shfl_xor(r, o);
    if (lane == e) mine = r;
  }
  if (lane < E_T) logits[(size_t)token * E_T + lane] = mine;
}

// ---------------- kernel 2b: softmax + top-k, one thread per token ----------------
__global__ void k_topk(const float* __restrict__ logits, const float* __restrict__ bias,
                       float* __restrict__ zero_w, int* __restrict__ counts,
                       int* __restrict__ tok_list, float* __restrict__ wt_list) {
  int t = blockIdx.x * 64 + threadIdx.x;
  float l[E_T];
  const float4* lp = reinterpret_cast<const float4*>(logits + (size_t)t * E_T);
  #pragma unroll
  for (int j = 0; j < E_T / 4; ++j) {
    float4 v = lp[j];
    l[j * 4 + 0] = v.x; l[j * 4 + 1] = v.y; l[j * 4 + 2] = v.z; l[j * 4 + 3] = v.w;
  }
  float m = -FLT_MAX;
  #pragma unroll
  for (int e = 0; e < E_T; ++e) m = fmaxf(m, l[e]);
  float den = 0.f;
  #pragma unroll
  for (int e = 0; e < E_T; ++e) { l[e] = __expf(l[e] - m); den += l[e]; }
  float inv = 1.f / den;
  float sel[E_T];
  #pragma unroll
  for (int e = 0; e < E_T; ++e) { l[e] *= inv; sel[e] = l[e] + bias[e]; }

  unsigned long long used = 0ull;
  float zw = 0.f;
  for (int k = 0; k < TOPK; ++k) {
    float bv = -FLT_MAX; int bj = 0;
    #pragma unroll
    for (int e = 0; e < E_T; ++e) {                // all indices compile-time: no scratch
      float v = ((used >> e) & 1ull) ? -FLT_MAX : sel[e];
      if (v > bv) { bv = v; bj = e; }
    }
    used |= 1ull << bj;
    float wgt = (bv - bias[bj]) * SCALE_F;         // score = sel - bias; bias via global (L2-hot)
    if (bj >= E_R) {
      zw += wgt;
    } else {
      int p = atomicAdd(&counts[bj], 1);
      tok_list[bj * TT + p] = t;
      wt_list[bj * TT + p] = wgt;
    }
  }
  zero_w[t] = zw;
}

// ---------------- kernel 3: prefix scan of counts ----------------
__global__ void k_scan(const int* __restrict__ counts, int* __restrict__ offsets) {
  if (threadIdx.x == 0) {
    int s = 0;
    for (int e = 0; e < E_R; ++e) { offsets[e] = s; s += counts[e]; }
    offsets[E_R] = s;
  }
}

// ---------------- kernel 4: out = x * zero_w ----------------
__global__ void k_init_out(const float* __restrict__ x, const float* __restrict__ zero_w,
                           float* __restrict__ out) {
  int i = blockIdx.x * 256 + threadIdx.x;          // one per 4 floats
  int t = i >> 8;                                  // 256 float4 per row
  float zw = zero_w[t];
  float4 v = reinterpret_cast<const float4*>(x)[i];
  v.x *= zw; v.y *= zw; v.z *= zw; v.w *= zw;
  reinterpret_cast<float4*>(out)[i] = v;
}

// ---------------- kernel 5: grouped GEMM1 + SiLU*up -> inter (bf16) ----------------
// block: 64 token-rows x (64 gate cols + 64 up cols), K = 1024
__global__ __launch_bounds__(256) void k_gemm1(
    const unsigned short* __restrict__ xb, const float* __restrict__ gup,
    const int* __restrict__ tok_list, const int* __restrict__ counts,
    const int* __restrict__ offsets, unsigned short* __restrict__ inter) {
  const int e = blockIdx.z;
  const int cnt = counts[e];
  const int row0 = blockIdx.y * 64;
  if (row0 >= cnt) return;
  const int n0 = blockIdx.x * 64;
  const int off = offsets[e];
  const int tid = threadIdx.x;
  const int lane = tid & 63;
  const int wave = tid >> 6;
  const int wr = wave >> 1, wc = wave & 1;

  __shared__ __align__(16) unsigned short lA[64 * 64];
  __shared__ __align__(16) unsigned short lBg[64 * 64];
  __shared__ __align__(16) unsigned short lBu[64 * 64];
  __shared__ int toks[64];

  if (tid < 64) {
    int r = row0 + tid;
    toks[tid] = tok_list[e * TT + (r < cnt ? r : cnt - 1)];
  }
  __syncthreads();

  f32x4 accg[2][2] = {}; f32x4 accu[2][2] = {};

  for (int k0 = 0; k0 < HH; k0 += 64) {
    #pragma unroll
    for (int c = tid; c < 512; c += 256) {
      int row = c >> 3, c8 = c & 7;
      uint4 v = *reinterpret_cast<const uint4*>(xb + (size_t)toks[row] * HH + (k0 + c8 * 8));
      lds_store16(lA, row, c8, v);
      const float4* p = reinterpret_cast<const float4*>(
          gup + ((size_t)e * 1024 + (n0 + row)) * HH + (k0 + c8 * 8));
      lds_store16(lBg, row, c8, cvt8(p[0], p[1]));
      const float4* q = reinterpret_cast<const float4*>(
          gup + ((size_t)e * 1024 + (512 + n0 + row)) * HH + (k0 + c8 * 8));
      lds_store16(lBu, row, c8, cvt8(q[0], q[1]));
    }
    __syncthreads();
    #pragma unroll
    for (int ks = 0; ks < 2; ++ks) {
      int kb = ks * 32 + ((lane >> 4) << 3);
      bf16x8 a0 = lds_frag(lA, wr * 32 + (lane & 15), kb);
      bf16x8 a1 = lds_frag(lA, wr * 32 + 16 + (lane & 15), kb);
      bf16x8 g0 = lds_frag(lBg, wc * 32 + (lane & 15), kb);
      bf16x8 g1 = lds_frag(lBg, wc * 32 + 16 + (lane & 15), kb);
      bf16x8 u0 = lds_frag(lBu, wc * 32 + (lane & 15), kb);
      bf16x8 u1 = lds_frag(lBu, wc * 32 + 16 + (lane & 15), kb);
      accg[0][0] = mfma16(a0, g0, accg[0][0]);
      accg[0][1] = mfma16(a0, g1, accg[0][1]);
      accg[1][0] = mfma16(a1, g0, accg[1][0]);
      accg[1][1] = mfma16(a1, g1, accg[1][1]);
      accu[0][0] = mfma16(a0, u0, accu[0][0]);
      accu[0][1] = mfma16(a0, u1, accu[0][1]);
      accu[1][0] = mfma16(a1, u0, accu[1][0]);
      accu[1][1] = mfma16(a1, u1, accu[1][1]);
    }
    __syncthreads();
  }

  #pragma unroll
  for (int i = 0; i < 2; ++i)
    #pragma unroll
    for (int j = 0; j < 2; ++j)
      #pragma unroll
      for (int r = 0; r < 4; ++r) {
        int rloc = wr * 32 + i * 16 + ((lane >> 4) << 2) + r;
        int grow = row0 + rloc;
        if (grow < cnt) {
          int col = n0 + wc * 32 + j * 16 + (lane & 15);
          float g = accg[i][j][r], u = accu[i][j][r];
          float act = g * (1.f / (1.f + __expf(-g))) * u;
          inter[(size_t)(off + grow) * II + col] = f2bf(act);
        }
      }
}

// ---------------- kernel 6: grouped GEMM2, scatter-add into out ----------------
// block: 64 rows x 64 out cols, K = 512
__global__ __launch_bounds__(256) void k_gemm2(
    const unsigned short* __restrict__ inter, const float* __restrict__ dwn,
    const int* __restrict__ tok_list, const float* __restrict__ wt_list,
    const int* __restrict__ counts, const int* __restrict__ offsets,
    float* __restrict__ out) {
  const int e = blockIdx.z;
  const int cnt = counts[e];
  const int row0 = blockIdx.y * 64;
  if (row0 >= cnt) return;
  const int n0 = blockIdx.x * 64;
  const int off = offsets[e];
  const int tid = threadIdx.x;
  const int lane = tid & 63;
  const int wave = tid >> 6;
  const int wr = wave >> 1, wc = wave & 1;

  __shared__ __align__(16) unsigned short lA[64 * 64];
  __shared__ __align__(16) unsigned short lB[64 * 64];
  __shared__ int toks[64];
  __shared__ float wts[64];

  if (tid < 64) {
    int r = row0 + tid;
    int rc = r < cnt ? r : cnt - 1;
    toks[tid] = tok_list[e * TT + rc];
    wts[tid] = (r < cnt) ? wt_list[e * TT + rc] : 0.f;
  }
  __syncthreads();

  f32x4 acc[2][2] = {};

  for (int k0 = 0; k0 < II; k0 += 64) {
    #pragma unroll
    for (int c = tid; c < 512; c += 256) {
      int row = c >> 3, c8 = c & 7;
      int rr = row0 + row; rr = rr < cnt ? rr : cnt - 1;
      uint4 v = *reinterpret_cast<const uint4*>(inter + (size_t)(off + rr) * II + (k0 + c8 * 8));
      lds_store16(lA, row, c8, v);
      const float4* p = reinterpret_cast<const float4*>(
          dwn + ((size_t)e * HH + (n0 + row)) * II + (k0 + c8 * 8));
      lds_store16(lB, row, c8, cvt8(p[0], p[1]));
    }
    __syncthreads();
    #pragma unroll
    for (int ks = 0; ks < 2; ++ks) {
      int kb = ks * 32 + ((lane >> 4) << 3);
      bf16x8 a0 = lds_frag(lA, wr * 32 + (lane & 15), kb);
      bf16x8 a1 = lds_frag(lA, wr * 32 + 16 + (lane & 15), kb);
      bf16x8 b0 = lds_frag(lB, wc * 32 + (lane & 15), kb);
      bf16x8 b1 = lds_frag(lB, wc * 32 + 16 + (lane & 15), kb);
      acc[0][0] = mfma16(a0, b0, acc[0][0]);
      acc[0][1] = mfma16(a0, b1, acc[0][1]);
      acc[1][0] = mfma16(a1, b0, acc[1][0]);
      acc[1][1] = mfma16(a1, b1, acc[1][1]);
    }
    __syncthreads();
  }

  #pragma unroll
  for (int i = 0; i < 2; ++i)
    #pragma unroll
    for (int j = 0; j < 2; ++j)
      #pragma unroll
      for (int r = 0; r < 4; ++r) {
        int rloc = wr * 32 + i * 16 + ((lane >> 4) << 2) + r;
        int grow = row0 + rloc;
        if (grow < cnt) {
          int h = n0 + wc * 32 + j * 16 + (lane & 15);
          unsafeAtomicAdd(&out[(size_t)toks[rloc] * HH + h], acc[i][j][r] * wts[rloc]);
        }
      }
}

// ---------------- ws layout ----------------
// xb      : TT*HH bf16          =  8,388,608 B   @ 0
// zero_w  : TT f32              =     16,384 B   @ 8,388,608
// counts  : 32 i32              =        128 B   @ 8,404,992
// offsets : 33 i32 (pad 256)    =        256 B   @ 8,405,120
// tok_list: 32*TT i32           =    524,288 B   @ 8,405,376
// wt_list : 32*TT f32           =    524,288 B   @ 8,929,664
// logits  : TT*E_T f32          =    655,360 B   @ 9,453,952
// inter   : 24576*II bf16       = 25,165,824 B   @ 10,109,312
// total ~= 35.3 MB

extern "C" void kernel_launch(void* const* d_in, const int* in_sizes, int n_in,
                              void* d_out, int out_size, void* d_ws, size_t ws_size,
                              hipStream_t stream) {
  const float* x    = (const float*)d_in[0];
  const float* wcls = (const float*)d_in[1];
  const float* bias = (const float*)d_in[2];
  const float* gup  = (const float*)d_in[3];
  const float* dwn  = (const float*)d_in[4];
  float* out = (float*)d_out;

  char* w = (char*)d_ws;
  unsigned short* xb   = (unsigned short*)(w + 0);
  float* zero_w        = (float*)(w + 8388608);
  int* counts          = (int*)(w + 8404992);
  int* offsets         = (int*)(w + 8405120);
  int* tok_list        = (int*)(w + 8405376);
  float* wt_list       = (float*)(w + 8929664);
  float* logits        = (float*)(w + 9453952);
  unsigned short* inter = (unsigned short*)(w + 10109312);

  hipMemsetAsync(counts, 0, E_R * sizeof(int), stream);
  k_convert_x<<<2048, 256, 0, stream>>>(x, xb);
  k_logits<<<1024, 256, 0, stream>>>(x, wcls, logits);
  k_topk<<<64, 64, 0, stream>>>(logits, bias, zero_w, counts, tok_list, wt_list);
  k_scan<<<1, 64, 0, stream>>>(counts, offsets);
  k_init_out<<<4096, 256, 0, stream>>>(x, zero_w, out);
  k_gemm1<<<dim3(8, 64, E_R), 256, 0, stream>>>(xb, gup, tok_list, counts, offsets, inter);
  k_gemm2<<<dim3(16, 64, E_R), 256, 0, stream>>>(inter, dwn, tok_list, wt_list, counts, offsets, out);
}